// Round 1
// 443.984 us; speedup vs baseline: 1.1418x; 1.1418x over previous
//
#include <hip/hip_runtime.h>

// CrossNet (DCN cross layers), B=16384, D=4096, L=6, fp32.
// Algebraic form: x_l = x0 * a_l + c_l, with
//   c_l = sum_{i<l} b_i                (row-independent vector, precomputed)
//   d_l = c_l . w_l                    (row-independent scalar, precomputed)
//   u_l = x0 . w_l                     (6 independent per-row dots)
//   a_0 = 1;  a_{l+1} = a_l*(1+u_l) + d_l
//   out  = x0 * a_L + c_L
//
// This version: persistent-style blocks. 2048 blocks x 8 rows; each thread
// keeps its slice of w (6 x float4) and c (2 x float4) in REGISTERS for all
// 8 rows (kills the 1.8 GB of per-block w/c L2 re-read traffic), and
// prefetches the next row's x into registers so HBM loads stay in flight
// under the reduce/barrier/store phases.

#define BATCH   16384
#define DIM     4096
#define NLAYER  6
#define BLK     512
#define VPT     2            // float4 per thread: DIM/4/BLK
#define NWAVE   (BLK / 64)   // 8 waves per block
#define ROWS    8
#define NBLOCKS (BATCH / ROWS)  // 2048

// ---- precompute c_L[D] and d[NLAYER] into workspace (1 block) ----
__global__ __launch_bounds__(1024) void precompute_kernel(
    const float* __restrict__ w,     // [L, D]
    const float* __restrict__ bias,  // [L, D]
    float* __restrict__ c_out,       // [D]
    float* __restrict__ d_out)       // [NLAYER]
{
    const int tid  = threadIdx.x;         // 0..1023
    const int lane = tid & 63;
    const int wave = tid >> 6;            // 0..15

    float dpart[NLAYER];
#pragma unroll
    for (int l = 0; l < NLAYER; ++l) dpart[l] = 0.0f;

#pragma unroll
    for (int k = 0; k < DIM / 1024; ++k) {
        const int j = tid + k * 1024;
        float pre = 0.0f;                 // prefix sum of bias over layers at j
#pragma unroll
        for (int l = 0; l < NLAYER; ++l) {
            dpart[l] = fmaf(pre, w[l * DIM + j], dpart[l]);
            pre += bias[l * DIM + j];
        }
        c_out[j] = pre;                   // c_L[j] = sum of all layer biases
    }

#pragma unroll
    for (int l = 0; l < NLAYER; ++l)
#pragma unroll
        for (int off = 32; off > 0; off >>= 1)
            dpart[l] += __shfl_xor(dpart[l], off, 64);

    __shared__ float red[16][NLAYER];
    if (lane == 0)
#pragma unroll
        for (int l = 0; l < NLAYER; ++l) red[wave][l] = dpart[l];
    __syncthreads();
    if (tid < NLAYER) {
        float s = 0.0f;
#pragma unroll
        for (int wv = 0; wv < 16; ++wv) s += red[wv][tid];
        d_out[tid] = s;
    }
}

// ---- main kernel: one block per 8 rows, w/c register-resident ----
__global__ __launch_bounds__(BLK, 4) void crossnet_kernel(
    const float* __restrict__ xin,
    const float* __restrict__ w,    // [L, D]
    const float* __restrict__ c,    // [D]   (c_L)
    const float* __restrict__ d,    // [NLAYER]
    float* __restrict__ out)
{
    const int tid  = threadIdx.x;
    const int lane = tid & 63;
    const int wave = tid >> 6;
    const size_t base = (size_t)blockIdx.x * ROWS;

    // ---- load per-thread slices of w, c, d once; registers for all rows ----
    float4 wreg[NLAYER][VPT];
#pragma unroll
    for (int l = 0; l < NLAYER; ++l) {
        const float4* wl = (const float4*)(w + l * DIM);
#pragma unroll
        for (int j = 0; j < VPT; ++j) wreg[l][j] = wl[tid + j * BLK];
    }
    float4 creg[VPT];
    const float4* cp = (const float4*)c;
#pragma unroll
    for (int j = 0; j < VPT; ++j) creg[j] = cp[tid + j * BLK];

    float dl[NLAYER];
#pragma unroll
    for (int l = 0; l < NLAYER; ++l) dl[l] = d[l];

    __shared__ float red[2][NWAVE][NLAYER];   // double-buffered: 1 barrier/row

    // ---- prime: load row 0 ----
    float4 xc[VPT], xn[VPT];
    {
        const float4* xr = (const float4*)(xin + base * DIM);
#pragma unroll
        for (int j = 0; j < VPT; ++j) xc[j] = xr[tid + j * BLK];
    }

#pragma unroll
    for (int r = 0; r < ROWS; ++r) {
        // prefetch next row's x early; consumed only after store of this row
        if (r + 1 < ROWS) {
            const float4* xr = (const float4*)(xin + (base + r + 1) * DIM);
#pragma unroll
            for (int j = 0; j < VPT; ++j) xn[j] = xr[tid + j * BLK];
        }

        // 6 independent partial dots of x0 row against each w_l (registers)
        float u[NLAYER];
#pragma unroll
        for (int l = 0; l < NLAYER; ++l) {
            float s = 0.0f;
#pragma unroll
            for (int j = 0; j < VPT; ++j) {
                s = fmaf(xc[j].x, wreg[l][j].x, s);
                s = fmaf(xc[j].y, wreg[l][j].y, s);
                s = fmaf(xc[j].z, wreg[l][j].z, s);
                s = fmaf(xc[j].w, wreg[l][j].w, s);
            }
            u[l] = s;
        }

        // butterfly within wave; all 6 values in one phase
#pragma unroll
        for (int l = 0; l < NLAYER; ++l)
#pragma unroll
            for (int off = 32; off > 0; off >>= 1)
                u[l] += __shfl_xor(u[l], off, 64);

        if (lane == 0)
#pragma unroll
            for (int l = 0; l < NLAYER; ++l) red[r & 1][wave][l] = u[l];
        __syncthreads();

        // scalar recurrence a_{l+1} = a_l*(1+s_l) + d_l (redundant per thread)
        float a = 1.0f;
#pragma unroll
        for (int l = 0; l < NLAYER; ++l) {
            float s = 0.0f;
#pragma unroll
            for (int wv = 0; wv < NWAVE; ++wv) s += red[r & 1][wv][l];
            a = fmaf(a, s, a) + dl[l];
        }

        // out = x0 * a + c   (c from registers)
        float4* orow = (float4*)(out + (base + r) * DIM);
#pragma unroll
        for (int j = 0; j < VPT; ++j) {
            float4 o;
            o.x = fmaf(xc[j].x, a, creg[j].x);
            o.y = fmaf(xc[j].y, a, creg[j].y);
            o.z = fmaf(xc[j].z, a, creg[j].z);
            o.w = fmaf(xc[j].w, a, creg[j].w);
            orow[tid + j * BLK] = o;
        }

        if (r + 1 < ROWS) {
#pragma unroll
            for (int j = 0; j < VPT; ++j) xc[j] = xn[j];
        }
    }
}

extern "C" void kernel_launch(void* const* d_in, const int* in_sizes, int n_in,
                              void* d_out, int out_size, void* d_ws, size_t ws_size,
                              hipStream_t stream) {
    const float* xin  = (const float*)d_in[0];   // [B, D]
    const float* w    = (const float*)d_in[1];   // [L, D, 1] == [L, D]
    const float* bias = (const float*)d_in[2];   // [L, D]
    float* out = (float*)d_out;                  // [B, D]

    float* c = (float*)d_ws;                     // [D]
    float* d = c + DIM;                          // [NLAYER]

    precompute_kernel<<<1, 1024, 0, stream>>>(w, bias, c, d);
    crossnet_kernel<<<NBLOCKS, BLK, 0, stream>>>(xin, w, c, d, out);
}